// Round 16
// baseline (919.479 us; speedup 1.0000x reference)
//
#include <hip/hip_runtime.h>

#define N_USERS 100000
#define N_ITEMS 50000
#define N_NODES 150000
#define EMBED_DIM 64

#define BUCKET_SHIFT 9                 // 512 rows per bucket
#define BUCKET_ROWS 512
#define NB 293                         // ceil(150000 / 512)
#define NBLK 2048                      // partition blocks (scanA assumes == 8*256)
#define NBIN 10                        // col bins: col>>14, max 149999>>14 = 9

__device__ inline unsigned short f_to_bf(float f) {
    unsigned u = __float_as_uint(f);
    return (unsigned short)((u + 0x7FFFu + ((u >> 16) & 1u)) >> 16);   // RNE
}
__device__ inline float bf_lo(int w) { return __uint_as_float((unsigned)w << 16); }
__device__ inline float bf_hi(int w) { return __uint_as_float((unsigned)w & 0xFFFF0000u); }

// ===========================================================================
// init: out = concat(user,item) fp32 ; x_bf = bf16(concat)
// ===========================================================================
__global__ void init_kernel(const float4* __restrict__ user,
                            const float4* __restrict__ item,
                            ushort4* __restrict__ xbf,
                            float4* __restrict__ acc,
                            int n_user4, int total4) {
    int i = blockIdx.x * blockDim.x + threadIdx.x;
    if (i < total4) {
        float4 v = (i < n_user4) ? user[i] : item[i - n_user4];
        acc[i] = v;
        ushort4 b;
        b.x = f_to_bf(v.x); b.y = f_to_bf(v.y);
        b.z = f_to_bf(v.z); b.w = f_to_bf(v.w);
        xbf[i] = b;
    }
}

// ===========================================================================
// P0: per-block LDS histogram over 512-row buckets (no global atomics)
// ===========================================================================
__global__ __launch_bounds__(256) void part_count_kernel(const int* __restrict__ rows,
                                                         int* __restrict__ blk_cnt, int nnz) {
    __shared__ int cnt[NB];
    for (int i = threadIdx.x; i < NB; i += 256) cnt[i] = 0;
    __syncthreads();
    int b = blockIdx.x;
    int chunk = (nnz + NBLK - 1) / NBLK;
    int s = b * chunk, e = min(nnz, s + chunk);
    for (int i = s + threadIdx.x; i < e; i += 256)
        atomicAdd(&cnt[rows[i] >> BUCKET_SHIFT], 1);
    __syncthreads();
    for (int i = threadIdx.x; i < NB; i += 256) blk_cnt[b * NB + i] = cnt[i];
}

// ===========================================================================
// scanA: per bucket, exclusive scan over NBLK per-block counts (8/thread)
// ===========================================================================
__global__ __launch_bounds__(256) void scan_blocks_kernel(int* __restrict__ blk_cnt,
                                                          int* __restrict__ bkt_tot) {
    __shared__ int psum[256];
    int nb = blockIdx.x, tid = threadIdx.x;
    int v[8]; int s = 0;
#pragma unroll
    for (int j = 0; j < 8; ++j) {
        v[j] = blk_cnt[(8 * tid + j) * NB + nb];
        s += v[j];
    }
    psum[tid] = s; __syncthreads();
    for (int off = 1; off < 256; off <<= 1) {
        int t = (tid >= off) ? psum[tid - off] : 0;
        __syncthreads();
        psum[tid] += t;
        __syncthreads();
    }
    int run = psum[tid] - s;
#pragma unroll
    for (int j = 0; j < 8; ++j) {
        blk_cnt[(8 * tid + j) * NB + nb] = run;
        run += v[j];
    }
    if (tid == 255) bkt_tot[nb] = psum[255];
}

// ===========================================================================
// scanB: exclusive scan over NB bucket totals -> bucket_start[NB+1]
// ===========================================================================
__global__ __launch_bounds__(256) void scan_buckets_kernel(const int* __restrict__ bkt_tot,
                                                           int* __restrict__ bucket_start, int nnz) {
    __shared__ int lds[256];
    int tid = threadIdx.x;
    int v[2]; int s = 0;
#pragma unroll
    for (int j = 0; j < 2; ++j) {
        int idx = tid * 2 + j;
        v[j] = (idx < NB) ? bkt_tot[idx] : 0;
        s += v[j];
    }
    lds[tid] = s; __syncthreads();
    for (int off = 1; off < 256; off <<= 1) {
        int t = (tid >= off) ? lds[tid - off] : 0;
        __syncthreads();
        lds[tid] += t;
        __syncthreads();
    }
    int run = lds[tid] - s;
#pragma unroll
    for (int j = 0; j < 2; ++j) {
        int idx = tid * 2 + j;
        if (idx < NB) bucket_start[idx] = run;
        run += v[j];
    }
    if (tid == 0) bucket_start[NB] = nnz;
}

// ===========================================================================
// P1: partition edges into bucket-ordered part[] via LDS cursors
// entry: (local_row<<18 | col, val_bits)  local_row<512, col<2^18
// ===========================================================================
__global__ __launch_bounds__(256) void partition_kernel(const int* __restrict__ rows,
                                                        const int* __restrict__ cols,
                                                        const float* __restrict__ vals,
                                                        const int* __restrict__ blk_cnt,
                                                        const int* __restrict__ bucket_start,
                                                        int2* __restrict__ part, int nnz) {
    __shared__ int cur[NB];
    int b = blockIdx.x;
    for (int i = threadIdx.x; i < NB; i += 256)
        cur[i] = bucket_start[i] + blk_cnt[b * NB + i];
    __syncthreads();
    int chunk = (nnz + NBLK - 1) / NBLK;
    int s = b * chunk, e = min(nnz, s + chunk);
    for (int i = s + threadIdx.x; i < e; i += 256) {
        int r = rows[i];
        int nb = r >> BUCKET_SHIFT;
        int rl = r & (BUCKET_ROWS - 1);
        int pos = atomicAdd(&cur[nb], 1);
        part[pos] = make_int2((rl << 18) | cols[i], __float_as_int(vals[i]));
    }
}

// ===========================================================================
// P2a: per bucket, counting sort by col-bin (col>>14, 10 bins) -> csorted
// ballot-aggregated LDS atomics (few cursors -> heavy contention otherwise)
// ===========================================================================
__global__ __launch_bounds__(1024) void colbin_sort_kernel(const int2* __restrict__ part,
                                                           const int* __restrict__ bucket_start,
                                                           int2* __restrict__ csorted) {
    __shared__ int cnt[NBIN];
    __shared__ int off[NBIN];
    int nb = blockIdx.x, tid = threadIdx.x;
    int lane = tid & 63;
    int base = bucket_start[nb];
    int cntE = bucket_start[nb + 1] - base;

    if (tid < NBIN) cnt[tid] = 0;
    __syncthreads();

    for (int i = tid; i < cntE; i += 1024) {
        int bin = (part[base + i].x & 0x3FFFF) >> 14;
#pragma unroll
        for (int b = 0; b < NBIN; ++b) {
            unsigned long long m = __ballot(bin == b);
            if (bin == b) {
                int pre = __popcll(m & ((1ull << lane) - 1ull));
                if (pre == 0) atomicAdd(&cnt[b], __popcll(m));
            }
        }
    }
    __syncthreads();
    if (tid == 0) {
        int run = 0;
        for (int b = 0; b < NBIN; ++b) { off[b] = run; run += cnt[b]; }
    }
    __syncthreads();

    for (int i = tid; i < cntE; i += 1024) {
        int2 ev = part[base + i];
        int bin = (ev.x & 0x3FFFF) >> 14;
        int pos = 0;
#pragma unroll
        for (int b = 0; b < NBIN; ++b) {
            unsigned long long m = __ballot(bin == b);
            if (bin == b) {
                int pre = __popcll(m & ((1ull << lane) - 1ull));
                int ldr = __ffsll((unsigned long long)m) - 1;
                int bp = 0;
                if (pre == 0) bp = atomicAdd(&off[b], __popcll(m));
                bp = __shfl(bp, ldr, 64);
                pos = bp + pre;
            }
        }
        csorted[base + pos] = ev;
    }
}

// ===========================================================================
// P2b: per bucket, counting sort by local row (512 bins) of the col-binned
// stream -> final edges (col,val) + row_ptr. Arrival order preserves the
// coarse col order within each row.
// ===========================================================================
__global__ __launch_bounds__(1024) void bucket_sort_kernel(const int2* __restrict__ csorted,
                                                           const int* __restrict__ bucket_start,
                                                           int* __restrict__ row_ptr,
                                                           int2* __restrict__ edges, int nnz) {
    __shared__ int cnt[BUCKET_ROWS];
    __shared__ int off[BUCKET_ROWS];
    __shared__ int psum[256];
    int nb = blockIdx.x, tid = threadIdx.x;
    int base = bucket_start[nb];
    int cntE = bucket_start[nb + 1] - base;

    if (tid < BUCKET_ROWS) cnt[tid] = 0;
    __syncthreads();
    for (int i = tid; i < cntE; i += 1024)
        atomicAdd(&cnt[csorted[base + i].x >> 18], 1);
    __syncthreads();

    int c0 = 0, c1 = 0, s = 0;
    if (tid < 256) {
        c0 = cnt[2 * tid]; c1 = cnt[2 * tid + 1];
        s = c0 + c1;
        psum[tid] = s;
    }
    __syncthreads();
    for (int o = 1; o < 256; o <<= 1) {
        int t = 0;
        if (tid < 256 && tid >= o) t = psum[tid - o];
        __syncthreads();
        if (tid < 256) psum[tid] += t;
        __syncthreads();
    }
    if (tid < 256) {
        int excl = psum[tid] - s;
        off[2 * tid] = excl;
        off[2 * tid + 1] = excl + c0;
        int r0 = nb << BUCKET_SHIFT;
        int ra = r0 + 2 * tid, rb = ra + 1;
        if (ra < N_NODES) row_ptr[ra] = base + excl;
        if (rb < N_NODES) row_ptr[rb] = base + excl + c0;
    }
    __syncthreads();

    for (int i = tid; i < cntE; i += 1024) {
        int2 ev = csorted[base + i];
        int rl = ev.x >> 18;
        int rank = atomicAdd(&off[rl], 1);
        edges[base + rank] = make_int2(ev.x & 0x3FFFF, ev.y);
    }
    if (nb == 0 && tid == 0) row_ptr[N_NODES] = nnz;
}

// ===========================================================================
// Row-parallel gather SpMM, bf16 x via int4 (16B/lane, 8 lanes/edge),
// 16 edges/iter (2 chains x 8 groups); fp32 accumulate; shfl_xor reduce.
// ===========================================================================
__global__ __launch_bounds__(256) void spmm_csr_kernel(
        const int* __restrict__ row_ptr, const int2* __restrict__ edges,
        const int4* __restrict__ x16,
        ushort4* __restrict__ ybf, float4* __restrict__ out4,
        float final_scale, int write_y) {
    int wid = (blockIdx.x * blockDim.x + threadIdx.x) >> 6;   // wave id = row
    int lane = threadIdx.x & 63;
    if (wid >= N_NODES) return;

    int start = row_ptr[wid];
    int nj = row_ptr[wid + 1] - start;
    int g  = lane >> 3;     // group 0..7
    int gl = lane & 7;      // 16B chunk (8 dims) of the 64-dim row

    const int2* ep = edges + start;
    float a0[8] = {0,0,0,0,0,0,0,0};
    float a1[8] = {0,0,0,0,0,0,0,0};

    int jmax = (nj + 15) >> 4;   // 16 edges per iteration
    for (int j = 0; j < jmax; ++j) {
        int i0 = (j << 4) + g;
        int i1 = i0 + 8;
        bool ok0 = i0 < nj;
        bool ok1 = i1 < nj;
        int2 e0 = ep[ok0 ? i0 : 0];
        int2 e1 = ep[ok1 ? i1 : 0];
        float v0 = ok0 ? __int_as_float(e0.y) : 0.0f;
        float v1 = ok1 ? __int_as_float(e1.y) : 0.0f;
        int4 q0 = x16[e0.x * 8 + gl];
        int4 q1 = x16[e1.x * 8 + gl];
        a0[0] += v0 * bf_lo(q0.x);  a0[1] += v0 * bf_hi(q0.x);
        a0[2] += v0 * bf_lo(q0.y);  a0[3] += v0 * bf_hi(q0.y);
        a0[4] += v0 * bf_lo(q0.z);  a0[5] += v0 * bf_hi(q0.z);
        a0[6] += v0 * bf_lo(q0.w);  a0[7] += v0 * bf_hi(q0.w);
        a1[0] += v1 * bf_lo(q1.x);  a1[1] += v1 * bf_hi(q1.x);
        a1[2] += v1 * bf_lo(q1.y);  a1[3] += v1 * bf_hi(q1.y);
        a1[4] += v1 * bf_lo(q1.z);  a1[5] += v1 * bf_hi(q1.z);
        a1[6] += v1 * bf_lo(q1.w);  a1[7] += v1 * bf_hi(q1.w);
    }

    float a[8];
#pragma unroll
    for (int k = 0; k < 8; ++k) a[k] = a0[k] + a1[k];

#pragma unroll
    for (int off = 8; off < 64; off <<= 1) {
#pragma unroll
        for (int k = 0; k < 8; ++k) a[k] += __shfl_xor(a[k], off, 64);
    }

    if (lane < 8) {
        int o = wid * 16 + gl * 2;
        if (write_y) {
            ushort4 b0, b1;
            b0.x = f_to_bf(a[0]); b0.y = f_to_bf(a[1]);
            b0.z = f_to_bf(a[2]); b0.w = f_to_bf(a[3]);
            b1.x = f_to_bf(a[4]); b1.y = f_to_bf(a[5]);
            b1.z = f_to_bf(a[6]); b1.w = f_to_bf(a[7]);
            ybf[o] = b0; ybf[o + 1] = b1;
        }
        float4 ov = out4[o];
        ov.x = (ov.x + a[0]) * final_scale;
        ov.y = (ov.y + a[1]) * final_scale;
        ov.z = (ov.z + a[2]) * final_scale;
        ov.w = (ov.w + a[3]) * final_scale;
        out4[o] = ov;
        float4 ow = out4[o + 1];
        ow.x = (ow.x + a[4]) * final_scale;
        ow.y = (ow.y + a[5]) * final_scale;
        ow.z = (ow.z + a[6]) * final_scale;
        ow.w = (ow.w + a[7]) * final_scale;
        out4[o + 1] = ow;
    }
}

// ===========================================================================
extern "C" void kernel_launch(void* const* d_in, const int* in_sizes, int n_in,
                              void* d_out, int out_size, void* d_ws, size_t ws_size,
                              hipStream_t stream) {
    const float* user = (const float*)d_in[0];
    const float* item = (const float*)d_in[1];
    const int*   rows = (const int*)d_in[2];
    const int*   cols = (const int*)d_in[3];
    const float* vals = (const float*)d_in[4];
    float* out = (float*)d_out;

    const int nnz = in_sizes[2];
    const size_t nfloats = (size_t)N_NODES * EMBED_DIM;   // 9.6M
    const int total4 = (int)(nfloats / 4);
    const int n_user4 = (N_USERS * EMBED_DIM) / 4;

    // ---- workspace layout (256B-aligned regions) ----
    // Dataflow: P1 -> part; P2a: part -> csorted(@o_csort); P2b: csorted ->
    // final edges (@o_part, reusing it); xbf/ybf overlay o_csort (dead after P2b).
    char* ws = (char*)d_ws;
    size_t off = 0;
    auto alloc = [&](size_t bytes) { size_t p = off; off += (bytes + 255) & ~(size_t)255; return p; };
    size_t o_part   = alloc(((size_t)nnz + 8) * sizeof(int2));   // 64 MB
    size_t o_rptr   = alloc((N_NODES + 1) * sizeof(int));
    size_t o_blkcnt = alloc((size_t)NBLK * NB * sizeof(int));    // 2.4 MB
    size_t o_btot   = alloc((NB + 1) * sizeof(int));
    size_t o_bstart = alloc((NB + 1) * sizeof(int));
    size_t o_csort  = alloc(((size_t)nnz + 8) * sizeof(int2));   // 64 MB

    int2* part    = (int2*)(ws + o_part);
    int* row_ptr  = (int*)(ws + o_rptr);
    int* blk_cnt  = (int*)(ws + o_blkcnt);
    int* bkt_tot  = (int*)(ws + o_btot);
    int* bstart   = (int*)(ws + o_bstart);
    int2* csorted = (int2*)(ws + o_csort);
    int2* edges   = part;                       // final edges overwrite part
    ushort4* xbf  = (ushort4*)(ws + o_csort);   // overlay csorted after P2b
    ushort4* ybf  = (ushort4*)(ws + o_csort + (size_t)N_NODES * EMBED_DIM * 2);
    (void)ws_size;

    // ---- CSR build: two-level LDS counting sort + col-bin ordering ----
    part_count_kernel<<<NBLK, 256, 0, stream>>>(rows, blk_cnt, nnz);
    scan_blocks_kernel<<<NB, 256, 0, stream>>>(blk_cnt, bkt_tot);
    scan_buckets_kernel<<<1, 256, 0, stream>>>(bkt_tot, bstart, nnz);
    partition_kernel<<<NBLK, 256, 0, stream>>>(rows, cols, vals, blk_cnt, bstart, part, nnz);
    colbin_sort_kernel<<<NB, 1024, 0, stream>>>(part, bstart, csorted);
    bucket_sort_kernel<<<NB, 1024, 0, stream>>>(csorted, bstart, row_ptr, edges, nnz);

    // ---- init: out = emb (fp32), x_bf = bf16(emb) ----
    int iblocks = (total4 + 255) / 256;
    init_kernel<<<iblocks, 256, 0, stream>>>((const float4*)user, (const float4*)item,
                                             xbf, (float4*)out, n_user4, total4);

    // ---- 3 fused gather-SpMM layers (bf16 state, fp32 accumulate) ----
    ushort4* x = xbf; ushort4* y = ybf;
    int sblocks = (N_NODES * 64 + 255) / 256;   // 1 wave per row
    for (int layer = 0; layer < 3; ++layer) {
        float fs = (layer == 2) ? 0.25f : 1.0f;
        int wy = (layer == 2) ? 0 : 1;
        spmm_csr_kernel<<<sblocks, 256, 0, stream>>>(row_ptr, edges,
                                                     (const int4*)x,
                                                     y, (float4*)out, fs, wy);
        ushort4* t = x; x = y; y = t;
    }
}